// Round 1
// baseline (4543.698 us; speedup 1.0000x reference)
//
#include <hip/hip_runtime.h>

using u32 = unsigned int;
using u64 = unsigned long long;
using bf16x8 = __attribute__((ext_vector_type(8))) short;
using f32x4  = __attribute__((ext_vector_type(4))) float;

// Problem constants
#define BB_ 64
#define TT_ 512
#define II_ 1024
#define HH_ 1024
#define NSCAN_BLOCKS 128

__device__ __forceinline__ unsigned short bf16rne(float f) {
  u32 u = __float_as_uint(f);
  return (unsigned short)((u + 0x7FFFu + ((u >> 16) & 1u)) >> 16);
}
__device__ __forceinline__ u32 pk2(float a, float b) {
  u32 ua = __float_as_uint(a), ub = __float_as_uint(b);
  u32 lo = (ua + 0x7FFFu + ((ua >> 16) & 1u)) >> 16;
  u32 hi = (ub + 0x7FFFu + ((ub >> 16) & 1u)) & 0xFFFF0000u;
  return lo | hi;
}
__device__ __forceinline__ void gll16(const void* g, void* s) {
  __builtin_amdgcn_global_load_lds(
      (const __attribute__((address_space(1))) u32*)g,
      (__attribute__((address_space(3))) u32*)s, 16, 0, 0);
}

__device__ __forceinline__ void cvt4(const float* __restrict__ s, unsigned short* __restrict__ d, long long g) {
  float4 v = ((const float4*)s)[g];
  ushort4 o;
  o.x = bf16rne(v.x); o.y = bf16rne(v.y); o.z = bf16rne(v.z); o.w = bf16rne(v.w);
  ((ushort4*)d)[g] = o;
}

// ---------------------------------------------------------------------------
// k_convert: bf16 copies of x / W_ih / [W_hh1;W_hh2], hbuf[0]=bf16(h0), cnt=0
// Re-runs fully each launch -> graph-replay deterministic.
// ---------------------------------------------------------------------------
__global__ void k_convert(const float* __restrict__ x, const float* __restrict__ h0,
                          const float* __restrict__ Wih, const float* __restrict__ Wh1,
                          const float* __restrict__ Wh2,
                          unsigned short* __restrict__ xb, unsigned short* __restrict__ Wihb,
                          unsigned short* __restrict__ Wcatb, unsigned short* __restrict__ hbuf,
                          int* __restrict__ cnt, int do_x) {
  const long long NWI = (long long)HH_ * II_ / 4;      // 262144 float4 groups
  const long long NH0 = (long long)BB_ * HH_ / 4;      // 16384
  const long long NC  = 128;                           // 512 ints / int4
  const long long NX  = do_x ? ((long long)BB_ * TT_ * II_ / 4) : 0;
  const long long total = 3 * NWI + NH0 + NC + NX;
  for (long long g = (long long)blockIdx.x * blockDim.x + threadIdx.x; g < total;
       g += (long long)gridDim.x * blockDim.x) {
    if (g < NWI) {
      cvt4(Wih, Wihb, g);
    } else if (g < 2 * NWI) {
      cvt4(Wh1, Wcatb, g - NWI);
    } else if (g < 3 * NWI) {
      cvt4(Wh2, Wcatb + (long long)HH_ * II_, g - 2 * NWI);
    } else if (g < 3 * NWI + NH0) {
      cvt4(h0, hbuf, g - 3 * NWI);
    } else if (g < 3 * NWI + NH0 + NC) {
      ((int4*)cnt)[g - 3 * NWI - NH0] = make_int4(0, 0, 0, 0);
    } else {
      cvt4(x, xb, g - (3 * NWI + NH0 + NC));
    }
  }
}

// ---------------------------------------------------------------------------
// k_gemm: xp[m][n] = sum_k x[m][k] * Wih[n][k] + b_ih[n], written into d_out.
// 128x128 tile, BK=64, 4 waves (2x2 of 64x64), mfma 16x16x32 bf16.
// LDS 16B-chunk XOR swizzle (chunk ^= row&7) -> 2-way-free bank pattern.
// XB=true: A staged from pre-converted bf16 via global_load_lds (16B).
// XB=false: A staged from fp32 x with inline convert (ws too small fallback).
// ---------------------------------------------------------------------------
template <bool XB>
__global__ __launch_bounds__(256) void k_gemm(const unsigned short* __restrict__ xbg,
                                              const float* __restrict__ xf,
                                              const unsigned short* __restrict__ Wb,
                                              const float* __restrict__ bias,
                                              float* __restrict__ C) {
  __shared__ __align__(16) unsigned short ldsA[128 * 64];
  __shared__ __align__(16) unsigned short ldsB[128 * 64];
  const int tid = threadIdx.x;
  const int w = tid >> 6, l = tid & 63;
  const int lr = l & 15, lk = l >> 4;
  const int n0 = (blockIdx.x & 7) * 128;
  const int m0 = (blockIdx.x >> 3) * 128;
  const int mbase = (w >> 1) * 64, nbase = (w & 1) * 64;

  f32x4 acc[4][4] = {};

  for (int kb = 0; kb < 16; ++kb) {
    const int k0 = kb * 64;
    // ---- stage B (always bf16 source) ----
#pragma unroll
    for (int r = 0; r < 4; ++r) {
      int tb = r * 4096 + w * 1024 + l * 16;  // byte offset in 16KB tile
      int row = tb >> 7;
      int p = (tb >> 4) & 7;
      int c = p ^ (row & 7);
      gll16(Wb + (u64)(n0 + row) * II_ + k0 + c * 8,
            (char*)ldsB + r * 4096 + w * 1024);
    }
    // ---- stage A ----
    if constexpr (XB) {
#pragma unroll
      for (int r = 0; r < 4; ++r) {
        int tb = r * 4096 + w * 1024 + l * 16;
        int row = tb >> 7;
        int p = (tb >> 4) & 7;
        int c = p ^ (row & 7);
        gll16(xbg + (u64)(m0 + row) * II_ + k0 + c * 8,
              (char*)ldsA + r * 4096 + w * 1024);
      }
    } else {
      const int r = tid >> 1, ch = tid & 1;  // 2 threads/row, 32 floats each
      const float* gs = xf + (u64)(m0 + r) * II_ + k0 + ch * 32;
      float4 v[8];
#pragma unroll
      for (int q = 0; q < 8; ++q) v[q] = ((const float4*)gs)[q];
#pragma unroll
      for (int q = 0; q < 4; ++q) {
        int c = ch * 4 + q;
        int p = c ^ (r & 7);
        uint4 pk;
        pk.x = pk2(v[2 * q].x, v[2 * q].y);
        pk.y = pk2(v[2 * q].z, v[2 * q].w);
        pk.z = pk2(v[2 * q + 1].x, v[2 * q + 1].y);
        pk.w = pk2(v[2 * q + 1].z, v[2 * q + 1].w);
        *(uint4*)((char*)ldsA + r * 128 + p * 16) = pk;
      }
    }
    __syncthreads();

    bf16x8 a[4][2], b[4][2];
#pragma unroll
    for (int mt = 0; mt < 4; ++mt) {
      int row = mbase + mt * 16 + lr;
#pragma unroll
      for (int kk = 0; kk < 2; ++kk) {
        int c = kk * 4 + lk, p = c ^ (row & 7);
        a[mt][kk] = *(const bf16x8*)((const char*)ldsA + row * 128 + p * 16);
      }
    }
#pragma unroll
    for (int nt = 0; nt < 4; ++nt) {
      int row = nbase + nt * 16 + lr;
#pragma unroll
      for (int kk = 0; kk < 2; ++kk) {
        int c = kk * 4 + lk, p = c ^ (row & 7);
        b[nt][kk] = *(const bf16x8*)((const char*)ldsB + row * 128 + p * 16);
      }
    }
#pragma unroll
    for (int kk = 0; kk < 2; ++kk)
#pragma unroll
      for (int mt = 0; mt < 4; ++mt)
#pragma unroll
        for (int nt = 0; nt < 4; ++nt)
          acc[mt][nt] = __builtin_amdgcn_mfma_f32_16x16x32_bf16(a[mt][kk], b[nt][kk], acc[mt][nt], 0, 0, 0);
    __syncthreads();
  }

  float bn[4];
#pragma unroll
  for (int nt = 0; nt < 4; ++nt) bn[nt] = bias[n0 + nbase + nt * 16 + lr];
#pragma unroll
  for (int mt = 0; mt < 4; ++mt) {
#pragma unroll
    for (int i = 0; i < 4; ++i) {
      int m = m0 + mbase + mt * 16 + lk * 4 + i;
      float* cr = C + (u64)m * HH_ + n0 + nbase + lr;
#pragma unroll
      for (int nt = 0; nt < 4; ++nt) cr[nt * 16] = acc[mt][nt][i] + bn[nt];
    }
  }
}

// ---------------------------------------------------------------------------
// k_scan: persistent recurrent scan.
// 128 blocks = 32 j-groups (32 h-cols each) x 4 batch-groups (16 rows each).
// 4 waves/block = K-split by 256. Each wave holds its 4x(16 out)x256 weight
// slice in 128 VGPRs (loaded once). Per step:
//   waves: 8x dwordx4 h-frag loads (bf16, from hbuf[t&1]) + 32 MFMA
//   waves 1-3 dump partials to LDS; wave0 reduces, adds xp (read from d_out,
//   which still holds xp at [b][t]), tanh gates with fp32 h kept in registers,
//   writes h_t to d_out and bf16 h to hbuf[(t+1)&1].
// One release-atomicAdd / acquire-spin counter barrier per step (agent scope
// handles cross-XCD L2 non-coherence). Double buffer + full barrier => safe.
// ---------------------------------------------------------------------------
__global__ __launch_bounds__(256) void k_scan(float* __restrict__ out, const float* __restrict__ h0,
                                              const float* __restrict__ b1, const float* __restrict__ b2,
                                              const unsigned short* __restrict__ Wcat,
                                              unsigned short* __restrict__ hbuf, int* __restrict__ cnt) {
  __shared__ __align__(16) float part[3 * 4 * 256];  // [wave-1][nt][lane*4]
  const int tid = threadIdx.x, w = tid >> 6, l = tid & 63;
  const int lr = l & 15, lk = l >> 4;
  const int og = blockIdx.x & 31, bg = blockIdx.x >> 5;
  const int jb = og * 32, bb = bg * 16;
  const int koff = w * 256;

  // --- persistent weights: wt[nt][kk], nt 0/1 -> W_hh1 rows, 2/3 -> W_hh2 ---
  bf16x8 wt[4][8];
#pragma unroll
  for (int nt = 0; nt < 4; ++nt) {
    int nrow = (nt < 2) ? (jb + nt * 16 + lr) : (HH_ + jb + (nt - 2) * 16 + lr);
    const unsigned short* wr = Wcat + (u64)nrow * HH_ + koff + lk * 8;
#pragma unroll
    for (int kk = 0; kk < 8; ++kk) wt[nt][kk] = *(const bf16x8*)(wr + kk * 32);
  }

  // --- wave0 persistent fp32 state ---
  f32x4 hold[2];
  float bv1[2], bv2[2];
  if (w == 0) {
#pragma unroll
    for (int jj = 0; jj < 2; ++jj) {
#pragma unroll
      for (int i = 0; i < 4; ++i)
        hold[jj][i] = h0[(u64)(bb + lk * 4 + i) * HH_ + jb + jj * 16 + lr];
      bv1[jj] = b1[jb + jj * 16 + lr];
      bv2[jj] = b2[jb + jj * 16 + lr];
    }
  }

  for (int t = 0; t < TT_; ++t) {
    // prefetch xp for this step (independent of the barrier)
    float xpv[2][4];
    if (w == 0) {
#pragma unroll
      for (int jj = 0; jj < 2; ++jj)
#pragma unroll
        for (int i = 0; i < 4; ++i)
          xpv[jj][i] = out[((u64)(bb + lk * 4 + i) * TT_ + t) * HH_ + jb + jj * 16 + lr];
    }
    if (t > 0) {
      if (tid == 0) {
        while (__hip_atomic_load(cnt + t - 1, __ATOMIC_RELAXED, __HIP_MEMORY_SCOPE_AGENT) < NSCAN_BLOCKS) {}
        (void)__hip_atomic_load(cnt + t - 1, __ATOMIC_ACQUIRE, __HIP_MEMORY_SCOPE_AGENT);
      }
      __syncthreads();
    }

    const unsigned short* hb = hbuf + (t & 1) * (BB_ * HH_);
    const unsigned short* ha = hb + (u64)(bb + lr) * HH_ + koff + lk * 8;
    bf16x8 a[8];
#pragma unroll
    for (int kk = 0; kk < 8; ++kk) a[kk] = *(const bf16x8*)(ha + kk * 32);

    f32x4 acc[4] = {};
#pragma unroll
    for (int kk = 0; kk < 8; ++kk)
#pragma unroll
      for (int nt = 0; nt < 4; ++nt)
        acc[nt] = __builtin_amdgcn_mfma_f32_16x16x32_bf16(a[kk], wt[nt][kk], acc[nt], 0, 0, 0);

    if (w > 0) {
#pragma unroll
      for (int nt = 0; nt < 4; ++nt)
        *(f32x4*)&part[((w - 1) * 4 + nt) * 256 + l * 4] = acc[nt];
    }
    __syncthreads();

    if (w == 0) {
#pragma unroll
      for (int nt = 0; nt < 4; ++nt)
#pragma unroll
        for (int ww = 0; ww < 3; ++ww)
          acc[nt] += *(const f32x4*)&part[(ww * 4 + nt) * 256 + l * 4];

      unsigned short* hw = hbuf + ((t + 1) & 1) * (BB_ * HH_);
#pragma unroll
      for (int jj = 0; jj < 2; ++jj) {
#pragma unroll
        for (int i = 0; i < 4; ++i) {
          float s1 = acc[jj][i] + xpv[jj][i] + bv1[jj];
          float s2 = acc[jj + 2][i] + xpv[jj][i] + bv2[jj];
          float v1 = tanhf(s1), v2 = tanhf(s2);
          float h = hold[jj][i];
          float hn = v1 + h * (v2 - v1);  // (1-h)*v1 + h*v2
          hold[jj][i] = hn;
          int m = bb + lk * 4 + i, j = jb + jj * 16 + lr;
          out[((u64)m * TT_ + t) * HH_ + j] = hn;
          if (t < TT_ - 1)
            hw[(u64)m * HH_ + j] = bf16rne(hn);
          else
            out[(u64)BB_ * TT_ * HH_ + (u64)m * HH_ + j] = hn;
        }
      }
    }
    if (t < TT_ - 1) {
      if (tid == 0)
        __hip_atomic_fetch_add(cnt + t, 1, __ATOMIC_RELEASE, __HIP_MEMORY_SCOPE_AGENT);
    }
  }
}

// ---------------------------------------------------------------------------
extern "C" void kernel_launch(void* const* d_in, const int* in_sizes, int n_in,
                              void* d_out, int out_size, void* d_ws, size_t ws_size,
                              hipStream_t stream) {
  const float* x    = (const float*)d_in[0];
  const float* h0   = (const float*)d_in[1];
  const float* Wih  = (const float*)d_in[2];
  const float* bih  = (const float*)d_in[3];
  const float* Whh1 = (const float*)d_in[4];
  const float* bhh1 = (const float*)d_in[5];
  const float* Whh2 = (const float*)d_in[6];
  const float* bhh2 = (const float*)d_in[7];
  float* out = (float*)d_out;

  char* ws = (char*)d_ws;
  unsigned short* Wihb  = (unsigned short*)(ws + 0);          //  2 MiB
  unsigned short* Wcatb = (unsigned short*)(ws + 2097152);    //  4 MiB
  unsigned short* hbuf  = (unsigned short*)(ws + 6291456);    //  256 KiB
  int*            cnt   = (int*)(ws + 6553600);               //  2 KiB
  unsigned short* xb    = (unsigned short*)(ws + 6555648);    //  64 MiB
  const bool fastx = ws_size >= 73664512ULL;

  hipLaunchKernelGGL(k_convert, dim3(2048), dim3(256), 0, stream,
                     x, h0, Wih, Whh1, Whh2, xb, Wihb, Wcatb, hbuf, cnt, (int)fastx);
  if (fastx)
    hipLaunchKernelGGL((k_gemm<true>), dim3(2048), dim3(256), 0, stream,
                       xb, (const float*)nullptr, Wihb, bih, out);
  else
    hipLaunchKernelGGL((k_gemm<false>), dim3(2048), dim3(256), 0, stream,
                       (const unsigned short*)nullptr, x, Wihb, bih, out);
  hipLaunchKernelGGL(k_scan, dim3(NSCAN_BLOCKS), dim3(256), 0, stream,
                     out, h0, bhh1, bhh2, Wcatb, hbuf, cnt);
}

// Round 2
// 2335.550 us; speedup vs baseline: 1.9455x; 1.9455x over previous
//
#include <hip/hip_runtime.h>

using u32 = unsigned int;
using u64 = unsigned long long;
using bf16x8 = __attribute__((ext_vector_type(8))) short;
using f32x4  = __attribute__((ext_vector_type(4))) float;

// Problem constants
#define BB_ 64
#define TT_ 512
#define II_ 1024
#define HH_ 1024
#define NSCAN_BLOCKS 128
#define DOM 32  // blocks per batch-group domain

__device__ __forceinline__ unsigned short bf16rne(float f) {
  u32 u = __float_as_uint(f);
  return (unsigned short)((u + 0x7FFFu + ((u >> 16) & 1u)) >> 16);
}
__device__ __forceinline__ u32 pk2(float a, float b) {
  u32 ua = __float_as_uint(a), ub = __float_as_uint(b);
  u32 lo = (ua + 0x7FFFu + ((ua >> 16) & 1u)) >> 16;
  u32 hi = (ub + 0x7FFFu + ((ub >> 16) & 1u)) & 0xFFFF0000u;
  return lo | hi;
}
__device__ __forceinline__ void gll16(const void* g, void* s) {
  __builtin_amdgcn_global_load_lds(
      (const __attribute__((address_space(1))) u32*)g,
      (__attribute__((address_space(3))) u32*)s, 16, 0, 0);
}

__device__ __forceinline__ void cvt4(const float* __restrict__ s, unsigned short* __restrict__ d, long long g) {
  float4 v = ((const float4*)s)[g];
  ushort4 o;
  o.x = bf16rne(v.x); o.y = bf16rne(v.y); o.z = bf16rne(v.z); o.w = bf16rne(v.w);
  ((ushort4*)d)[g] = o;
}

// ---------------------------------------------------------------------------
// k_convert: bf16 copies of x / W_ih / [W_hh1;W_hh2], hbuf[0]=bf16(h0), flags=0
// ---------------------------------------------------------------------------
__global__ void k_convert(const float* __restrict__ x, const float* __restrict__ h0,
                          const float* __restrict__ Wih, const float* __restrict__ Wh1,
                          const float* __restrict__ Wh2,
                          unsigned short* __restrict__ xb, unsigned short* __restrict__ Wihb,
                          unsigned short* __restrict__ Wcatb, unsigned short* __restrict__ hbuf,
                          int* __restrict__ cnt, int do_x) {
  const long long NWI = (long long)HH_ * II_ / 4;
  const long long NH0 = (long long)BB_ * HH_ / 4;
  const long long NC  = 128;
  const long long NX  = do_x ? ((long long)BB_ * TT_ * II_ / 4) : 0;
  const long long total = 3 * NWI + NH0 + NC + NX;
  for (long long g = (long long)blockIdx.x * blockDim.x + threadIdx.x; g < total;
       g += (long long)gridDim.x * blockDim.x) {
    if (g < NWI) {
      cvt4(Wih, Wihb, g);
    } else if (g < 2 * NWI) {
      cvt4(Wh1, Wcatb, g - NWI);
    } else if (g < 3 * NWI) {
      cvt4(Wh2, Wcatb + (long long)HH_ * II_, g - 2 * NWI);
    } else if (g < 3 * NWI + NH0) {
      cvt4(h0, hbuf, g - 3 * NWI);
    } else if (g < 3 * NWI + NH0 + NC) {
      ((int4*)cnt)[g - 3 * NWI - NH0] = make_int4(0, 0, 0, 0);
    } else {
      cvt4(x, xb, g - (3 * NWI + NH0 + NC));
    }
  }
}

// ---------------------------------------------------------------------------
// k_gemm: xp = x @ Wih^T + b_ih, written into d_out. (unchanged, verified)
// ---------------------------------------------------------------------------
template <bool XB>
__global__ __launch_bounds__(256) void k_gemm(const unsigned short* __restrict__ xbg,
                                              const float* __restrict__ xf,
                                              const unsigned short* __restrict__ Wb,
                                              const float* __restrict__ bias,
                                              float* __restrict__ C) {
  __shared__ __align__(16) unsigned short ldsA[128 * 64];
  __shared__ __align__(16) unsigned short ldsB[128 * 64];
  const int tid = threadIdx.x;
  const int w = tid >> 6, l = tid & 63;
  const int lr = l & 15, lk = l >> 4;
  const int n0 = (blockIdx.x & 7) * 128;
  const int m0 = (blockIdx.x >> 3) * 128;
  const int mbase = (w >> 1) * 64, nbase = (w & 1) * 64;

  f32x4 acc[4][4] = {};

  for (int kb = 0; kb < 16; ++kb) {
    const int k0 = kb * 64;
#pragma unroll
    for (int r = 0; r < 4; ++r) {
      int tb = r * 4096 + w * 1024 + l * 16;
      int row = tb >> 7;
      int p = (tb >> 4) & 7;
      int c = p ^ (row & 7);
      gll16(Wb + (u64)(n0 + row) * II_ + k0 + c * 8,
            (char*)ldsB + r * 4096 + w * 1024);
    }
    if constexpr (XB) {
#pragma unroll
      for (int r = 0; r < 4; ++r) {
        int tb = r * 4096 + w * 1024 + l * 16;
        int row = tb >> 7;
        int p = (tb >> 4) & 7;
        int c = p ^ (row & 7);
        gll16(xbg + (u64)(m0 + row) * II_ + k0 + c * 8,
              (char*)ldsA + r * 4096 + w * 1024);
      }
    } else {
      const int r = tid >> 1, ch = tid & 1;
      const float* gs = xf + (u64)(m0 + r) * II_ + k0 + ch * 32;
      float4 v[8];
#pragma unroll
      for (int q = 0; q < 8; ++q) v[q] = ((const float4*)gs)[q];
#pragma unroll
      for (int q = 0; q < 4; ++q) {
        int c = ch * 4 + q;
        int p = c ^ (r & 7);
        uint4 pk;
        pk.x = pk2(v[2 * q].x, v[2 * q].y);
        pk.y = pk2(v[2 * q].z, v[2 * q].w);
        pk.z = pk2(v[2 * q + 1].x, v[2 * q + 1].y);
        pk.w = pk2(v[2 * q + 1].z, v[2 * q + 1].w);
        *(uint4*)((char*)ldsA + r * 128 + p * 16) = pk;
      }
    }
    __syncthreads();

    bf16x8 a[4][2], b[4][2];
#pragma unroll
    for (int mt = 0; mt < 4; ++mt) {
      int row = mbase + mt * 16 + lr;
#pragma unroll
      for (int kk = 0; kk < 2; ++kk) {
        int c = kk * 4 + lk, p = c ^ (row & 7);
        a[mt][kk] = *(const bf16x8*)((const char*)ldsA + row * 128 + p * 16);
      }
    }
#pragma unroll
    for (int nt = 0; nt < 4; ++nt) {
      int row = nbase + nt * 16 + lr;
#pragma unroll
      for (int kk = 0; kk < 2; ++kk) {
        int c = kk * 4 + lk, p = c ^ (row & 7);
        b[nt][kk] = *(const bf16x8*)((const char*)ldsB + row * 128 + p * 16);
      }
    }
#pragma unroll
    for (int kk = 0; kk < 2; ++kk)
#pragma unroll
      for (int mt = 0; mt < 4; ++mt)
#pragma unroll
        for (int nt = 0; nt < 4; ++nt)
          acc[mt][nt] = __builtin_amdgcn_mfma_f32_16x16x32_bf16(a[mt][kk], b[nt][kk], acc[mt][nt], 0, 0, 0);
    __syncthreads();
  }

  float bn[4];
#pragma unroll
  for (int nt = 0; nt < 4; ++nt) bn[nt] = bias[n0 + nbase + nt * 16 + lr];
#pragma unroll
  for (int mt = 0; mt < 4; ++mt) {
#pragma unroll
    for (int i = 0; i < 4; ++i) {
      int m = m0 + mbase + mt * 16 + lk * 4 + i;
      float* cr = C + (u64)m * HH_ + n0 + nbase + lr;
#pragma unroll
      for (int nt = 0; nt < 4; ++nt) cr[nt * 16] = acc[mt][nt][i] + bn[nt];
    }
  }
}

// ---------------------------------------------------------------------------
// k_scan v2: persistent recurrent scan, latency-optimized sync.
//  - 4 independent batch-group domains of 32 blocks; per-block FLAG word
//    (no central atomic counter -> no 128-way LLC RMW serialization).
//  - h exchanged via relaxed agent-scope atomic u64 ops (sc1: bypass the
//    non-coherent per-XCD L2s, served at the LLC coherence point). Ordering:
//    s_waitcnt vmcnt(0) + __syncthreads before the flag store. No
//    buffer_wbl2 / buffer_inv cache-maintenance per step.
//  - All 4 waves do the epilogue in parallel (partials via LDS transpose).
// ---------------------------------------------------------------------------
__global__ __launch_bounds__(256) void k_scan(float* __restrict__ out, const float* __restrict__ h0,
                                              const float* __restrict__ b1, const float* __restrict__ b2,
                                              const unsigned short* __restrict__ Wcat,
                                              unsigned short* __restrict__ hbuf, u32* __restrict__ flag) {
  __shared__ __align__(16) float part[4 * 4 * 4 * 64];      // [w][nt][i][lane] 16 KB
  __shared__ __align__(8) unsigned short hstage[16 * 32];   // 1 KB
  const int tid = threadIdx.x, w = tid >> 6, l = tid & 63;
  const int lr = l & 15, lk = l >> 4;
  const int og = blockIdx.x & 31, bg = blockIdx.x >> 5;
  const int jb = og * 32, bb = bg * 16;
  const int koff = w * 256;

  // --- persistent weights: wt[nt][kk], nt 0/1 -> W_hh1 rows, 2/3 -> W_hh2 ---
  bf16x8 wt[4][8];
#pragma unroll
  for (int nt = 0; nt < 4; ++nt) {
    int nrow = (nt < 2) ? (jb + nt * 16 + lr) : (HH_ + jb + (nt - 2) * 16 + lr);
    const unsigned short* wr = Wcat + (u64)nrow * HH_ + koff + lk * 8;
#pragma unroll
    for (int kk = 0; kk < 8; ++kk) wt[nt][kk] = *(const bf16x8*)(wr + kk * 32);
  }

  // --- epilogue role: wave w handles (jj = w&1, i in {i0, i0+1}) ---
  const int jj = w & 1, i0 = (w >> 1) * 2;
  const int jloc = jj * 16 + lr;   // 0..31
  const int jcol = jb + jloc;
  const float bvA = b1[jcol], bvB = b2[jcol];
  float hold[2];
#pragma unroll
  for (int q = 0; q < 2; ++q)
    hold[q] = h0[(u64)(bb + lk * 4 + i0 + q) * HH_ + jcol];

  u32* dflag = flag + bg * DOM;
  const u64 b4 = ((u64)(bb + lr) * HH_ + koff + lk * 8) >> 2;  // u64 index into h row

  for (int t = 0; t < TT_; ++t) {
    // prefetch xp (written by k_gemm; this block's slice is untouched until
    // our own write at step t, which is after this read in program order)
    float xpv[2];
#pragma unroll
    for (int q = 0; q < 2; ++q)
      xpv[q] = out[((u64)(bb + lk * 4 + i0 + q) * TT_ + t) * HH_ + jcol];

    if (t > 0) {
      if (w == 0) {
        const u32 need = (u32)t;
        while (true) {
          u32 v = (l < DOM)
                      ? __hip_atomic_load(dflag + l, __ATOMIC_RELAXED, __HIP_MEMORY_SCOPE_AGENT)
                      : 0xFFFFFFFFu;
          if (__all((int)(v >= need))) break;
        }
      }
      __syncthreads();
    }

    // --- load h_{t-1} fragments (LLC-direct u64 atomic loads) ---
    const u64* hB = (const u64*)hbuf + (u64)(t & 1) * (BB_ * HH_ / 4);
    u64 qv[16];
#pragma unroll
    for (int kk = 0; kk < 8; ++kk) {
      qv[2 * kk]     = __hip_atomic_load(hB + b4 + kk * 8,     __ATOMIC_RELAXED, __HIP_MEMORY_SCOPE_AGENT);
      qv[2 * kk + 1] = __hip_atomic_load(hB + b4 + kk * 8 + 1, __ATOMIC_RELAXED, __HIP_MEMORY_SCOPE_AGENT);
    }

    f32x4 acc[4] = {};
#pragma unroll
    for (int kk = 0; kk < 8; ++kk) {
      union { u64 q[2]; bf16x8 v; } au;
      au.q[0] = qv[2 * kk]; au.q[1] = qv[2 * kk + 1];
#pragma unroll
      for (int nt = 0; nt < 4; ++nt)
        acc[nt] = __builtin_amdgcn_mfma_f32_16x16x32_bf16(au.v, wt[nt][kk], acc[nt], 0, 0, 0);
    }

    // --- scatter partials to LDS, transposed for conflict-free combine ---
#pragma unroll
    for (int nt = 0; nt < 4; ++nt)
#pragma unroll
      for (int i = 0; i < 4; ++i)
        part[((w * 4 + nt) * 4 + i) * 64 + l] = acc[nt][i];
    __syncthreads();

    // --- parallel epilogue: each wave combines+activates its (jj, i) slice ---
    float hn2[2];
#pragma unroll
    for (int q = 0; q < 2; ++q) {
      const int i = i0 + q;
      float v1 = 0.f, v2 = 0.f;
#pragma unroll
      for (int ww = 0; ww < 4; ++ww) {
        v1 += part[((ww * 4 + jj) * 4 + i) * 64 + l];
        v2 += part[((ww * 4 + jj + 2) * 4 + i) * 64 + l];
      }
      float s1 = v1 + xpv[q] + bvA;
      float s2 = v2 + xpv[q] + bvB;
      float t1 = tanhf(s1), t2 = tanhf(s2);
      float h = hold[q];
      float hn = t1 + h * (t2 - t1);  // (1-h)*v1 + h*v2
      hold[q] = hn;
      hn2[q] = hn;
      out[((u64)(bb + lk * 4 + i) * TT_ + t) * HH_ + jcol] = hn;
      hstage[(lk * 4 + i) * 32 + jloc] = bf16rne(hn);
    }
    if (t == TT_ - 1) {
#pragma unroll
      for (int q = 0; q < 2; ++q)
        out[(u64)BB_ * TT_ * HH_ + (u64)(bb + lk * 4 + i0 + q) * HH_ + jcol] = hn2[q];
    }
    __syncthreads();  // hstage complete; also protects part[] reuse

    if (t < TT_ - 1) {
      if (tid < 128) {
        const int m = tid >> 3, c4 = tid & 7;
        u64 v = *(const u64*)&hstage[m * 32 + c4 * 4];
        u64* dst = (u64*)hbuf + (u64)((t + 1) & 1) * (BB_ * HH_ / 4) +
                   (((u64)(bb + m) * HH_ + jb + c4 * 4) >> 2);
        __hip_atomic_store(dst, v, __ATOMIC_RELAXED, __HIP_MEMORY_SCOPE_AGENT);
      }
      asm volatile("s_waitcnt vmcnt(0)" ::: "memory");
      __syncthreads();  // all waves' h stores acked at LLC
      if (tid == 0)
        __hip_atomic_store(dflag + og, (u32)(t + 1), __ATOMIC_RELAXED, __HIP_MEMORY_SCOPE_AGENT);
    }
  }
}

// ---------------------------------------------------------------------------
extern "C" void kernel_launch(void* const* d_in, const int* in_sizes, int n_in,
                              void* d_out, int out_size, void* d_ws, size_t ws_size,
                              hipStream_t stream) {
  const float* x    = (const float*)d_in[0];
  const float* h0   = (const float*)d_in[1];
  const float* Wih  = (const float*)d_in[2];
  const float* bih  = (const float*)d_in[3];
  const float* Whh1 = (const float*)d_in[4];
  const float* bhh1 = (const float*)d_in[5];
  const float* Whh2 = (const float*)d_in[6];
  const float* bhh2 = (const float*)d_in[7];
  float* out = (float*)d_out;

  char* ws = (char*)d_ws;
  unsigned short* Wihb  = (unsigned short*)(ws + 0);          //  2 MiB
  unsigned short* Wcatb = (unsigned short*)(ws + 2097152);    //  4 MiB
  unsigned short* hbuf  = (unsigned short*)(ws + 6291456);    //  256 KiB
  int*            cnt   = (int*)(ws + 6553600);               //  2 KiB (flags)
  unsigned short* xb    = (unsigned short*)(ws + 6555648);    //  64 MiB
  const bool fastx = ws_size >= 73664512ULL;

  hipLaunchKernelGGL(k_convert, dim3(2048), dim3(256), 0, stream,
                     x, h0, Wih, Whh1, Whh2, xb, Wihb, Wcatb, hbuf, cnt, (int)fastx);
  if (fastx)
    hipLaunchKernelGGL((k_gemm<true>), dim3(2048), dim3(256), 0, stream,
                       xb, (const float*)nullptr, Wihb, bih, out);
  else
    hipLaunchKernelGGL((k_gemm<false>), dim3(2048), dim3(256), 0, stream,
                       (const unsigned short*)nullptr, x, Wihb, bih, out);
  hipLaunchKernelGGL(k_scan, dim3(NSCAN_BLOCKS), dim3(256), 0, stream,
                     out, h0, bhh1, bhh2, Wcatb, hbuf, (u32*)cnt);
}